// Round 6
// baseline (177.022 us; speedup 1.0000x reference)
//
#include <hip/hip_runtime.h>
#include <math.h>

// Round 6: pairs-per-lane register pipeline with DPP lane-shifts.
// All lane+-1 gathers (16/trip) are v_mov_dpp wave_shr:1 / wave_shl:1 --
// VALU-rate, no DS pipe, no latency hop. Only the edge-strip x-reflect
// fixup keeps ds_bpermute. Global prefetch distance = 2 rows.
#define IMW 512
#define SEG 23
#define NSEG 23            // last seg shifted to Y0=489 (overlap, no waste)
#define NSTRIP 5           // last strip shifted to x0=396 (overlap, no waste)
#define OUTW 116
#define ITERS 7            // 7*5 = 35 = SEG+12 trips

#define DPP_WAVE_SHL1 0x130   // lane i <- lane i+1 (lane 63 keeps old)
#define DPP_WAVE_SHR1 0x138   // lane i <- lane i-1 (lane 0  keeps old)

__device__ __forceinline__ int reflect512(int i) {   // valid for [-511,1022]
    int a = i < 0 ? -i : i;
    int b = 1022 - a;
    return a < b ? a : b;
}
__device__ __forceinline__ float bperm(int a4, float v) {
    return __int_as_float(__builtin_amdgcn_ds_bpermute(a4, __float_as_int(v)));
}
// pull from lane-1 (invalid lane 0 keeps own value; halo lanes only)
__device__ __forceinline__ float shr1(float v) {
    int s = __float_as_int(v);
    return __int_as_float(__builtin_amdgcn_update_dpp(s, s, DPP_WAVE_SHR1, 0xF, 0xF, false));
}
// pull from lane+1 (invalid lane 63 keeps own value; halo lanes only)
__device__ __forceinline__ float shl1(float v) {
    int s = __float_as_int(v);
    return __int_as_float(__builtin_amdgcn_update_dpp(s, s, DPP_WAVE_SHL1, 0xF, 0xF, false));
}

template<bool XE, bool YE>
__device__ __forceinline__ void pipe_run(
    const float* __restrict__ c0p, const float* __restrict__ c1p,
    const float* __restrict__ c2p, float* __restrict__ outp,
    int Y0, int cb, bool inimgE, bool inimgO, bool stl,
    int srcE4, int srcO4, bool clampL, bool clampR)
{
    const float K0 = 0.054488684549643f, K1 = 0.244201342003233f, K2 = 0.402619946931554f;

    float hbE[5],hbO[5],hxE[5],hxO[5],hyE[5],hyO[5],mgE[5],mgO[5],cmE[5],cmO[5];
    int axE[5], axO[5];
    #pragma unroll
    for (int i = 0; i < 5; ++i) {
        hbE[i]=0.f;hbO[i]=0.f;hxE[i]=0.f;hxO[i]=0.f;hyE[i]=0.f;hyO[i]=0.f;
        mgE[i]=0.f;mgO[i]=0.f;cmE[i]=0.f;cmO[i]=0.f;axE[i]=0;axO[i]=0;
    }

    // prefetch rows v=Y0-6 (cur) and v=Y0-5 (nxt): distance-2 pipeline
    int ra = Y0 - 6, rb = Y0 - 5;
    if (YE) { ra = reflect512(ra); rb = reflect512(rb); }
    float2 a0 = *(const float2*)(c0p + (size_t)ra * IMW + cb);
    float2 a1 = *(const float2*)(c1p + (size_t)ra * IMW + cb);
    float2 a2 = *(const float2*)(c2p + (size_t)ra * IMW + cb);
    float2 b0 = *(const float2*)(c0p + (size_t)rb * IMW + cb);
    float2 b1 = *(const float2*)(c1p + (size_t)rb * IMW + cb);
    float2 b2 = *(const float2*)(c2p + (size_t)rb * IMW + cb);

    for (int it = 0; it < ITERS; ++it) {
        #pragma unroll
        for (int j = 0; j < 5; ++j) {
            const int t = it * 5 + j;
            const int v = Y0 - 6 + t;

            // ---- gray row v from cur; rotate nxt->cur; load row v+2 -> nxt
            float gE = 0.299f * a2.x + 0.587f * a1.x + 0.114f * a0.x;
            float gO = 0.299f * a2.y + 0.587f * a1.y + 0.114f * a0.y;
            a0 = b0; a1 = b1; a2 = b2;
            int rn = v + 2;
            rn = YE ? reflect512(rn) : min(rn, 511);
            b0 = *(const float2*)(c0p + (size_t)rn * IMW + cb);
            b1 = *(const float2*)(c1p + (size_t)rn * IMW + cb);
            b2 = *(const float2*)(c2p + (size_t)rn * IMW + cb);

            // ---- x-reflect fixup (edge strips only; identity elsewhere)
            if (XE) { gE = bperm(srcE4, gE); gO = bperm(srcO4, gO); }

            // ---- h-blur: taps ce-2..ce+2 / co-2..co+2 (DPP lane shifts)
            float eL = shr1(gE), eR = shl1(gE);
            float oL = shr1(gO), oR = shl1(gO);
            hbE[j] = K0 * (eL + eR) + K1 * (oL + gO) + K2 * gE;
            hbO[j] = K0 * (oL + oR) + K1 * (gE + eR) + K2 * gO;

            // ---- v-blur row v-2 (rows v-4..v = slots j+1,j+2,j+3,j+4,j)
            float bE = K0 * (hbE[(j+1)%5] + hbE[j]) + K1 * (hbE[(j+2)%5] + hbE[(j+4)%5]) + K2 * hbE[(j+3)%5];
            float bO = K0 * (hbO[(j+1)%5] + hbO[j]) + K1 * (hbO[(j+2)%5] + hbO[(j+4)%5]) + K2 * hbO[(j+3)%5];

            // ---- sobel h-passes row v-2 (x edge-clamp on edge strips)
            float oLb = shr1(bO);
            float eRb = shl1(bE);
            float nblE = XE ? (clampL ? bE : oLb) : oLb;   // blur[ce-1]
            float nbrO = XE ? (clampR ? bO : eRb) : eRb;   // blur[co+1]
            hxE[j] = bO - nblE;
            hyE[j] = nblE + 2.f * bE + bO;
            hxO[j] = nbrO - bE;
            hyO[j] = bE + 2.f * bO + nbrO;

            // ---- sobel v + mag + axis at row g = v-3 (rows g-1,g,g+1 = j+3,j+4,j)
            const int g = v - 3;
            float hxaE, hxcE, hyaE, hycE, hxaO, hxcO, hyaO, hycO;
            if (YE) {
                hxaE = (g == 0)   ? hxE[(j+4)%5] : hxE[(j+3)%5];
                hyaE = (g == 0)   ? hyE[(j+4)%5] : hyE[(j+3)%5];
                hxcE = (g == 511) ? hxE[(j+4)%5] : hxE[j];
                hycE = (g == 511) ? hyE[(j+4)%5] : hyE[j];
                hxaO = (g == 0)   ? hxO[(j+4)%5] : hxO[(j+3)%5];
                hyaO = (g == 0)   ? hyO[(j+4)%5] : hyO[(j+3)%5];
                hxcO = (g == 511) ? hxO[(j+4)%5] : hxO[j];
                hycO = (g == 511) ? hyO[(j+4)%5] : hyO[j];
            } else {
                hxaE = hxE[(j+3)%5]; hyaE = hyE[(j+3)%5]; hxcE = hxE[j]; hycE = hyE[j];
                hxaO = hxO[(j+3)%5]; hyaO = hyO[(j+3)%5]; hxcO = hxO[j]; hycO = hyO[j];
            }
            float gxE = (hxaE + 2.f * hxE[(j+4)%5] + hxcE) * 0.125f;
            float gyE = (hycE - hyaE) * 0.125f;
            float gxO = (hxaO + 2.f * hxO[(j+4)%5] + hxcO) * 0.125f;
            float gyO = (hycO - hyaO) * 0.125f;
            float magE = sqrtf(gxE * gxE + gyE * gyE + 1e-6f);
            float magO = sqrtf(gxO * gxO + gyO * gyO + 1e-6f);
            {
                float axm = fabsf(gxE), aym = fabsf(gyE);
                axE[j] = (aym <= 0.41421356237309515f * axm) ? 0
                       : (aym >= 2.4142135623730951f  * axm) ? 2
                       : (((gxE >= 0.f) == (gyE >= 0.f)) ? 1 : 3);
            }
            {
                float axm = fabsf(gxO), aym = fabsf(gyO);
                axO[j] = (aym <= 0.41421356237309515f * axm) ? 0
                       : (aym >= 2.4142135623730951f  * axm) ? 2
                       : (((gxO >= 0.f) == (gyO >= 0.f)) ? 1 : 3);
            }
            mgE[j] = inimgE ? magE : 0.f;
            mgO[j] = inimgO ? magO : 0.f;

            // ---- NMS row m = v-4 (rows m-1,m,m+1 = slots j+3, j+4, j)
            const int m = v - 4;
            float magcE = mgE[(j+4)%5], magcO = mgO[(j+4)%5];
            float magpE = mgE[j],       magpO = mgO[j];
            float magmE = mgE[(j+3)%5], magmO = mgO[(j+3)%5];
            if (YE) {
                if (m >= 511) { magpE = 0.f; magpO = 0.f; }
                if (m <= 0)   { magmE = 0.f; magmO = 0.f; }
            }
            float oLc = shr1(magcO), eRc = shl1(magcE);
            float oLp = shr1(magpO), eRp = shl1(magpE);
            float oLm = shr1(magmO), eRm = shl1(magmE);
            int dE = axE[(j+4)%5], dO = axO[(j+4)%5];
            float mpE = (dE == 0) ? magcO : (dE == 1) ? magpO : (dE == 2) ? magpE : oLp;
            float mnE = (dE == 0) ? oLc   : (dE == 1) ? oLm   : (dE == 2) ? magmE : magmO;
            float mpO = (dO == 0) ? eRc   : (dO == 1) ? eRp   : (dO == 2) ? magpO : magpE;
            float mnO = (dO == 0) ? magcE : (dO == 1) ? magmE : (dO == 2) ? magmO : eRm;
            float mskE = (fminf(magcE - mpE, magcE - mnE) > 0.f) ? magcE : 0.f;
            float mskO = (fminf(magcO - mpO, magcO - mnO) > 0.f) ? magcO : 0.f;

            // ---- horizontal 5-max row m
            float eLk = shr1(mskE), eRk = shl1(mskE);
            float oLk = shr1(mskO), oRk = shl1(mskO);
            float c4 = fmaxf(fmaxf(oLk, mskE), fmaxf(mskO, eRk));
            cmE[j] = fmaxf(c4, eLk);
            cmO[j] = fmaxf(c4, oRk);

            // ---- vertical 5-max -> out row y = v-6 (rows y-2..y+2 = j+1..j+4,j)
            if (t >= 12) {
                const int y = v - 6;
                float e0 = cmE[(j+1)%5], e1 = cmE[(j+2)%5], e2 = cmE[(j+3)%5];
                float e3 = cmE[(j+4)%5], e4 = cmE[j];
                float o0 = cmO[(j+1)%5], o1 = cmO[(j+2)%5], o2 = cmO[(j+3)%5];
                float o3 = cmO[(j+4)%5], o4 = cmO[j];
                if (YE) {
                    if (y < 2)   { e0 = 0.f; o0 = 0.f; if (y < 1)   { e1 = 0.f; o1 = 0.f; } }
                    if (y > 509) { e4 = 0.f; o4 = 0.f; if (y > 510) { e3 = 0.f; o3 = 0.f; } }
                }
                float2 val;
                val.x = fmaxf(fmaxf(fmaxf(e0, e1), fmaxf(e2, e3)), e4);
                val.y = fmaxf(fmaxf(fmaxf(o0, o1), fmaxf(o2, o3)), o4);
                if (stl) *(float2*)(outp + (size_t)y * IMW) = val;
            }
        }
    }
}

__global__ __launch_bounds__(256)
void canny_pipe(const float* __restrict__ x, float* __restrict__ out) {
    const int lane  = threadIdx.x & 63;
    const int unit  = blockIdx.x * 4 + (threadIdx.x >> 6);
    const int img   = unit / (NSTRIP * NSEG);
    const int rem   = unit - img * (NSTRIP * NSEG);
    const int strip = rem / NSEG;
    const int seg   = rem - strip * NSEG;

    int Y0 = seg * SEG;       if (seg == NSEG - 1)    Y0 = 512 - SEG;   // 489
    int Xs = strip * OUTW;    if (strip == NSTRIP - 1) Xs = 512 - OUTW; // 396
    const int X0 = Xs - 6;
    const int ce = X0 + 2 * lane, co = ce + 1;
    const int cb = min(max(ce, 0), 510);               // clamped even load col
    const bool inimgE = (unsigned)ce < 512u;
    const bool inimgO = (unsigned)co < 512u;
    const bool stl = (lane >= 3) && (lane <= 60);
    // x-reflect source lanes (parity-preserving; clamp keeps don't-care lanes safe)
    const int srcE4 = ((reflect512(min(max(ce, -2), 512)) - X0) >> 1) << 2;
    const int srcO4 = ((reflect512(min(max(co, -1), 513)) - X0 - 1) >> 1) << 2;
    const bool clampL = (ce == 0), clampR = (co == 511);

    const float* base = x + (size_t)img * 3 * IMW * IMW;
    const float* c0p = base;
    const float* c1p = base + (size_t)IMW * IMW;
    const float* c2p = base + (size_t)2 * IMW * IMW;
    float* outp = out + (size_t)img * IMW * IMW + ce;

    const bool xe = (strip == 0) || (strip == NSTRIP - 1);
    const bool ye = (seg == 0) || (seg == NSEG - 1);
    if (xe) {
        if (ye) pipe_run<true , true >(c0p,c1p,c2p,outp,Y0,cb,inimgE,inimgO,stl,srcE4,srcO4,clampL,clampR);
        else    pipe_run<true , false>(c0p,c1p,c2p,outp,Y0,cb,inimgE,inimgO,stl,srcE4,srcO4,clampL,clampR);
    } else {
        if (ye) pipe_run<false, true >(c0p,c1p,c2p,outp,Y0,cb,inimgE,inimgO,stl,srcE4,srcO4,clampL,clampR);
        else    pipe_run<false, false>(c0p,c1p,c2p,outp,Y0,cb,inimgE,inimgO,stl,srcE4,srcO4,clampL,clampR);
    }
}

extern "C" void kernel_launch(void* const* d_in, const int* in_sizes, int n_in,
                              void* d_out, int out_size, void* d_ws, size_t ws_size,
                              hipStream_t stream) {
    const float* x = (const float*)d_in[0];
    float* out = (float*)d_out;
    const int units = 32 * NSTRIP * NSEG;   // 3680 waves
    dim3 grid(units / 4);                   // 920 blocks, 4 waves each
    canny_pipe<<<grid, 256, 0, stream>>>(x, out);
}